// Round 6
// baseline (471.685 us; speedup 1.0000x reference)
//
#include <hip/hip_runtime.h>

#define EMBD 32
#define KN 10
#define GBLK 1024   // 4 blocks/CU x 256 CU; residency guaranteed (see launch_bounds note)

__device__ unsigned int g_cnt   = 0;
__device__ unsigned int g_epoch = 0;

__device__ __forceinline__ float bf2f(unsigned short u) {
    union { unsigned int u; float f; } c; c.u = ((unsigned int)u) << 16; return c.f;
}
__device__ __forceinline__ unsigned short f2bf(float f) {
    union { float f; unsigned int u; } c; c.f = f;
    unsigned int u = c.u + 0x7FFFu + ((c.u >> 16) & 1u);   // RNE
    return (unsigned short)(u >> 16);
}
__device__ __forceinline__ float bflo(unsigned int u) {
    union { unsigned int u; float f; } c; c.u = u << 16; return c.f;
}
__device__ __forceinline__ float bfhi(unsigned int u) {
    union { unsigned int u; float f; } c; c.u = u & 0xffff0000u; return c.f;
}

// Device-scope epoch barrier v2 (proven functional in R4; recovered the 6x
// collapse of R3's acquire-spin version). Steady state touches no cache
// maintenance: arrive = one ACQ_REL fetch_add (one wbl2/block), spin =
// RELAXED agent loads (no inv), exit = one acquire fence. Monotone epoch ->
// graph-replay safe. Requires all gridDim.x blocks resident:
// launch_bounds(256,4) caps VGPR at 128 -> >=4 blocks/CU; LDS 22272 B/block
// -> 7 blocks/CU by LDS; grid = 4 x 256 CU = 1024. OK.
__device__ __forceinline__ void gbar() {
    __syncthreads();                       // all block's stores drained to L2
    if (threadIdx.x == 0) {
        unsigned int e = __hip_atomic_load(&g_epoch, __ATOMIC_RELAXED,
                                           __HIP_MEMORY_SCOPE_AGENT);
        unsigned int a = __hip_atomic_fetch_add(&g_cnt, 1u, __ATOMIC_ACQ_REL,
                                                __HIP_MEMORY_SCOPE_AGENT);
        if (a == gridDim.x - 1) {
            __hip_atomic_store(&g_cnt, 0u, __ATOMIC_RELAXED,
                               __HIP_MEMORY_SCOPE_AGENT);
            __hip_atomic_fetch_add(&g_epoch, 1u, __ATOMIC_RELEASE,
                                   __HIP_MEMORY_SCOPE_AGENT);
        } else {
            while (__hip_atomic_load(&g_epoch, __ATOMIC_RELAXED,
                                     __HIP_MEMORY_SCOPE_AGENT) == e)
                __builtin_amdgcn_s_sleep(8);
            __builtin_amdgcn_fence(__ATOMIC_ACQUIRE, "agent");
        }
    }
    __syncthreads();
}

// ---- pipelined tile pieces (R5's verified tile body, reshaped) ----------

template<bool REMAP>
__device__ __forceinline__ void stage_idx(
    const int* __restrict__ neigh, const int* __restrict__ remap,
    int n_rows, int t, int (* __restrict__ s_nb)[KN], int* __restrict__ s_node,
    int tid)
{
    const int row0 = t << 6;
    if constexpr (REMAP) {
        if (tid < 64) {
            int r = row0 + tid;
            if (r >= n_rows) r = n_rows - 1;      // clamp; store guarded later
            s_node[tid] = remap[r];
        }
        __syncthreads();                          // block-uniform call sites only
    }
    #pragma unroll
    for (int e = tid; e < 64 * KN; e += 256) {
        const int rl = e / KN;
        const int k  = e - rl * KN;
        int node;
        if constexpr (REMAP) node = s_node[rl];
        else { int r = row0 + rl; node = (r >= n_rows) ? n_rows - 1 : r; }
        s_nb[rl][k] = neigh[node * KN + k];
    }
}

// issue the 11 quarter-row dwordx4 gathers for tile t into registers
template<bool REMAP>
__device__ __forceinline__ void issue_gather(
    const uint4* __restrict__ base, int n_rows, int t,
    const int (* __restrict__ s_nb)[KN], const int* __restrict__ s_node,
    int tid, uint4& sv, uint4* nv)
{
    const int g = tid >> 2;               // row slot 0..63
    const int q = tid & 3;                // 16 B quarter
    int node;
    if constexpr (REMAP) node = s_node[g];
    else { int r = (t << 6) + g; node = (r >= n_rows) ? n_rows - 1 : r; }
    sv = base[(size_t)node * 4 + q];
    #pragma unroll
    for (int k = 0; k < KN; ++k)
        nv[k] = base[(size_t)s_nb[g][k] * 4 + q];
}

__device__ __forceinline__ void unpack_to_sh(
    float (* __restrict__ sh)[65], const uint4& sv, const uint4* nv, int tid)
{
    const int g = tid >> 2;
    const int q = tid & 3;
    float a0=0.f,a1=0.f,a2=0.f,a3=0.f,a4=0.f,a5=0.f,a6=0.f,a7=0.f;
    #pragma unroll
    for (int k = 0; k < KN; ++k) {
        a0 += bflo(nv[k].x); a1 += bfhi(nv[k].x);
        a2 += bflo(nv[k].y); a3 += bfhi(nv[k].y);
        a4 += bflo(nv[k].z); a5 += bfhi(nv[k].z);
        a6 += bflo(nv[k].w); a7 += bfhi(nv[k].w);
    }
    const int f0 = q * 8;
    sh[f0+0][g] = bflo(sv.x); sh[f0+1][g] = bfhi(sv.x);
    sh[f0+2][g] = bflo(sv.y); sh[f0+3][g] = bfhi(sv.y);
    sh[f0+4][g] = bflo(sv.z); sh[f0+5][g] = bfhi(sv.z);
    sh[f0+6][g] = bflo(sv.w); sh[f0+7][g] = bfhi(sv.w);
    sh[32+f0+0][g] = a0 * 0.1f; sh[32+f0+1][g] = a1 * 0.1f;
    sh[32+f0+2][g] = a2 * 0.1f; sh[32+f0+3][g] = a3 * 0.1f;
    sh[32+f0+4][g] = a4 * 0.1f; sh[32+f0+5][g] = a5 * 0.1f;
    sh[32+f0+6][g] = a6 * 0.1f; sh[32+f0+7][g] = a7 * 0.1f;
}

template<bool OUT_BF16>
__device__ __forceinline__ void gemm_store(
    const float (* __restrict__ sh)[65], const float* __restrict__ W,
    void* __restrict__ out, int n_rows, int t, int tid)
{
    const int row = tid & 63;
    const int wid = __builtin_amdgcn_readfirstlane(tid >> 6);
    const float* Wb = W + wid * 8 * 64;   // wave-uniform -> scalar K$ loads

    float acc[8] = {0.f,0.f,0.f,0.f,0.f,0.f,0.f,0.f};
    #pragma unroll 8
    for (int jj = 0; jj < 64; ++jj) {
        const float c = sh[jj][row];      // stride-1 across lanes
        #pragma unroll
        for (int q = 0; q < 8; ++q)
            acc[q] = fmaf(c, Wb[q * 64 + jj], acc[q]);
    }

    const int r = (t << 6) + row;
    if (r < n_rows) {
        if constexpr (OUT_BF16) {
            unsigned int pk[4];
            #pragma unroll
            for (int q = 0; q < 4; ++q) {
                float a0 = fmaxf(acc[2*q],     0.f);
                float a1 = fmaxf(acc[2*q + 1], 0.f);
                pk[q] = (unsigned int)f2bf(a0) | ((unsigned int)f2bf(a1) << 16);
            }
            uint4* dst = (uint4*)((unsigned short*)out + (size_t)r * EMBD + wid * 8);
            *dst = make_uint4(pk[0], pk[1], pk[2], pk[3]);
        } else {
            float* dst = (float*)out + (size_t)r * EMBD + wid * 8;
            ((float4*)dst)[0] = make_float4(fmaxf(acc[0],0.f), fmaxf(acc[1],0.f),
                                            fmaxf(acc[2],0.f), fmaxf(acc[3],0.f));
            ((float4*)dst)[1] = make_float4(fmaxf(acc[4],0.f), fmaxf(acc[5],0.f),
                                            fmaxf(acc[6],0.f), fmaxf(acc[7],0.f));
        }
    }
}

// Software-pipelined grid-stride phase: gather(t+1) is ISSUED (into 44 regs)
// before GEMM(t) runs -> loads always in flight, so even if the CU's 4
// persistent blocks convoy (the R4 3.6x mystery: phase-locked gather/GEMM
// alternation with no block-replacement stream), memory never goes idle.
template<bool REMAP, bool OUT_BF16>
__device__ __forceinline__ void sage_phase(
    const unsigned short* __restrict__ feat, const float* __restrict__ W,
    const int* __restrict__ neigh, const int* __restrict__ remap,
    void* __restrict__ out, int n_rows,
    float (* __restrict__ sh)[65],
    int (* __restrict__ s_nb2)[64][KN], int (* __restrict__ s_node2)[64])
{
    const int tid = threadIdx.x;
    const int nt  = (n_rows + 63) >> 6;
    int t = blockIdx.x;
    if (t >= nt) return;                  // no tiles; gbar is outside the phase

    const uint4* base = (const uint4*)feat;
    uint4 sv, nv[KN];
    int cur = 0;

    // prologue: indices + gather issue for first tile
    stage_idx<REMAP>(neigh, remap, n_rows, t, s_nb2[0], s_node2[0], tid);
    __syncthreads();
    issue_gather<REMAP>(base, n_rows, t, s_nb2[0], s_node2[0], tid, sv, nv);

    while (true) {
        const int  tn       = t + (int)gridDim.x;
        const bool has_next = tn < nt;    // block-uniform

        __syncthreads();                  // GEMM(t-1) done: sh free, buf cur^1 free
        unpack_to_sh(sh, sv, nv, tid);    // waits only on gather regs
        if (has_next)
            stage_idx<REMAP>(neigh, remap, n_rows, tn,
                             s_nb2[cur ^ 1], s_node2[cur ^ 1], tid);
        __syncthreads();                  // sh ready; next indices ready
        if (has_next)
            issue_gather<REMAP>(base, n_rows, tn,
                                s_nb2[cur ^ 1], s_node2[cur ^ 1], tid, sv, nv);
        gemm_store<OUT_BF16>(sh, W, out, n_rows, t, tid);  // gather(t+1) in flight
        if (!has_next) break;
        cur ^= 1; t = tn;
    }
}

// Whole pipeline, one launch: cvt -> gbar -> L1 -> gbar -> L2.
// Envelope accounting R2/R4/R5: ~14 us per launch -> 3->1 saves ~28 us.
__global__ __launch_bounds__(256, 4)
void sage_all(const float4* __restrict__ emb4,       // [N*8]
              const float*  __restrict__ W1,
              const float*  __restrict__ W2,
              const int*    __restrict__ node_batch, // [B]
              const int*    __restrict__ neigh,      // [N,10]
              unsigned short* __restrict__ emb_bf,   // ws [N,32] bf16
              unsigned short* __restrict__ h1_bf,    // ws [N,32] bf16
              float*        __restrict__ out,        // [B,32] f32
              int N, int B)
{
    __shared__ float sh[64][65];          // 16640 B
    __shared__ int   s_nb2[2][64][KN];    //  5120 B
    __shared__ int   s_node2[2][64];      //   512 B  -> 22272 B total

    const int tid = threadIdx.x;

    // ---- phase 0: emb f32 -> bf16 (streaming) ----
    {
        ushort4* ob = (ushort4*)emb_bf;
        const int n4 = N * (EMBD / 4);
        for (int i = blockIdx.x * 256 + tid; i < n4; i += gridDim.x * 256) {
            float4 v = emb4[i];
            ushort4 o;
            o.x = f2bf(v.x); o.y = f2bf(v.y); o.z = f2bf(v.z); o.w = f2bf(v.w);
            ob[i] = o;
        }
    }
    gbar();

    // ---- phase 1: layer 1 over all N nodes, h1 bf16 ----
    sage_phase<false, true>(emb_bf, W1, neigh, nullptr, (void*)h1_bf, N,
                            sh, s_nb2, s_node2);
    gbar();

    // ---- phase 2: layer 2 over batch rows, f32 out ----
    sage_phase<true, false>(h1_bf, W2, neigh, node_batch, (void*)out, B,
                            sh, s_nb2, s_node2);
}

extern "C" void kernel_launch(void* const* d_in, const int* in_sizes, int n_in,
                              void* d_out, int out_size, void* d_ws, size_t ws_size,
                              hipStream_t stream)
{
    // dict order: emb [N,32] f32, W1 [32,64] f32, W2 [32,64] f32,
    //             node_batch [B] i32, neigh [N,10] i32
    const float* emb        = (const float*)d_in[0];
    const float* W1         = (const float*)d_in[1];
    const float* W2         = (const float*)d_in[2];
    const int*   node_batch = (const int*)  d_in[3];
    const int*   neigh      = (const int*)  d_in[4];

    const int N = in_sizes[0] / EMBD;   // 500000
    const int B = in_sizes[3];          // 100000

    unsigned short* emb_bf = (unsigned short*)d_ws;              // 32 MB
    unsigned short* h1_bf  = emb_bf + (size_t)N * EMBD;          // 32 MB

    sage_all<<<GBLK, 256, 0, stream>>>(
        (const float4*)emb, W1, W2, node_batch, neigh,
        emb_bf, h1_bf, (float*)d_out, N, B);
}

// Round 7
// 231.132 us; speedup vs baseline: 2.0408x; 2.0408x over previous
//
#include <hip/hip_runtime.h>

#define EMBD 32
#define KN 10

__device__ __forceinline__ float bf2f(unsigned short u) {
    union { unsigned int u; float f; } c; c.u = ((unsigned int)u) << 16; return c.f;
}
__device__ __forceinline__ unsigned short f2bf(float f) {
    union { float f; unsigned int u; } c; c.f = f;
    unsigned int u = c.u + 0x7FFFu + ((c.u >> 16) & 1u);   // RNE
    return (unsigned short)(u >> 16);
}
__device__ __forceinline__ float bflo(unsigned int u) {   // low bf16 of a uint
    union { unsigned int u; float f; } c; c.u = u << 16; return c.f;
}
__device__ __forceinline__ float bfhi(unsigned int u) {   // high bf16 of a uint
    union { unsigned int u; float f; } c; c.u = u & 0xffff0000u; return c.f;
}

// f32 -> bf16 table conversion (streaming, ~96 MB traffic, ~16 us @ stream ceiling)
__global__ __launch_bounds__(256)
void cvt_bf16_kernel(const float4* __restrict__ in, ushort4* __restrict__ out, int n4)
{
    int i = blockIdx.x * 256 + threadIdx.x;
    if (i < n4) {
        float4 v = in[i];
        ushort4 o;
        o.x = f2bf(v.x); o.y = f2bf(v.y); o.z = f2bf(v.z); o.w = f2bf(v.w);
        out[i] = o;
    }
}

// One SAGE layer, 64 rows per 256-thread block. 3-launch structure.
//
// ROOFLINE NOTES (verified R0-R6):
// - The random 64 B row-gather is sector-rate-limited at ~3.55 TB/s: four
//   independent structures (fused scalar, index-staged scalar, pure-gather
//   at 22 waves/CU, vectorized dwordx4) all land at 3.55 +/- 0.05 TB/s.
// - FETCH 299 MB ~= 17% above the 8-XCD cold-replication floor (8 x 32 MB
//   table + 43 MB neigh); 64 B sector granularity means fp8 rows would not
//   reduce sector count. Dedup within a tile is negligible (random ids).
// - GEMM adds only ~3 us over pure gather (fully hidden under loads).
// - Persistent single-launch variants (R3/R4/R6) all lost more to barrier
//   skew / occupancy / phase-convoy than the ~20 us of launch gaps saved.
template<bool REMAP, bool OUT_BF16>
__global__ __launch_bounds__(256, 4)
void sage_layer(const unsigned short* __restrict__ feat, // [n_nodes, 32] bf16
                const float* __restrict__ W,             // [32][64] f32
                const int*   __restrict__ neigh,         // [N_NODES, 10]
                const int*   __restrict__ remap,         // row -> node (REMAP)
                void*        __restrict__ out,           // [n_rows, 32]
                int n_rows)
{
    __shared__ float sh[64][65];          // 16640 B
    __shared__ int   s_nb[64][KN];        //  2560 B
    __shared__ int   s_node[64];          //   256 B

    const int tid  = threadIdx.x;
    const int row0 = blockIdx.x << 6;

    // ---- Phase A: node ids ----
    if constexpr (REMAP) {
        if (tid < 64) {
            int r = row0 + tid;
            if (r >= n_rows) r = n_rows - 1;       // clamp; store guarded later
            s_node[tid] = remap[r];                // coalesced 256 B
        }
        __syncthreads();
    }

    // ---- Phase B: stage all 640 neighbor ids, fully parallel ----
    #pragma unroll
    for (int e = tid; e < 64 * KN; e += 256) {
        const int rl = e / KN;
        const int k  = e - rl * KN;
        int node;
        if constexpr (REMAP) node = s_node[rl];
        else { int r = row0 + rl; node = (r >= n_rows) ? n_rows - 1 : r; }
        s_nb[rl][k] = neigh[node * KN + k];        // layer1: contiguous 2.5 KB
    }
    __syncthreads();

    // ---- Phase C: vectorized gather. thread (g,q): quarter q of row-slot g.
    {
        const int g = tid >> 2;           // row slot 0..63
        const int q = tid & 3;            // 16 B quarter of the 64 B row
        int node;
        if constexpr (REMAP) node = s_node[g];
        else { int r = row0 + g; node = (r >= n_rows) ? n_rows - 1 : r; }

        const uint4* base = (const uint4*)feat;    // row = 4 x uint4

        // issue all 11 dwordx4 loads; addresses depend only on LDS
        uint4 sv = base[(size_t)node * 4 + q];     // self quarter
        uint4 nv[KN];
        #pragma unroll
        for (int k = 0; k < KN; ++k)
            nv[k] = base[(size_t)s_nb[g][k] * 4 + q];

        float a0=0.f,a1=0.f,a2=0.f,a3=0.f,a4=0.f,a5=0.f,a6=0.f,a7=0.f;
        #pragma unroll
        for (int k = 0; k < KN; ++k) {
            a0 += bflo(nv[k].x); a1 += bfhi(nv[k].x);
            a2 += bflo(nv[k].y); a3 += bfhi(nv[k].y);
            a4 += bflo(nv[k].z); a5 += bfhi(nv[k].z);
            a6 += bflo(nv[k].w); a7 += bfhi(nv[k].w);
        }

        const int f0 = q * 8;             // first feature of this quarter
        sh[f0+0][g] = bflo(sv.x); sh[f0+1][g] = bfhi(sv.x);
        sh[f0+2][g] = bflo(sv.y); sh[f0+3][g] = bfhi(sv.y);
        sh[f0+4][g] = bflo(sv.z); sh[f0+5][g] = bfhi(sv.z);
        sh[f0+6][g] = bflo(sv.w); sh[f0+7][g] = bfhi(sv.w);
        sh[32+f0+0][g] = a0 * 0.1f; sh[32+f0+1][g] = a1 * 0.1f;
        sh[32+f0+2][g] = a2 * 0.1f; sh[32+f0+3][g] = a3 * 0.1f;
        sh[32+f0+4][g] = a4 * 0.1f; sh[32+f0+5][g] = a5 * 0.1f;
        sh[32+f0+6][g] = a6 * 0.1f; sh[32+f0+7][g] = a7 * 0.1f;
    }
    __syncthreads();

    // ---- compute phase: wave wid -> outputs [8*wid, 8*wid+8) ----
    const int row = tid & 63;
    const int wid = __builtin_amdgcn_readfirstlane(tid >> 6);
    const float* Wb = W + wid * 8 * 64;   // wave-uniform -> scalar K$ loads

    float acc[8] = {0.f,0.f,0.f,0.f,0.f,0.f,0.f,0.f};
    #pragma unroll 8
    for (int jj = 0; jj < 64; ++jj) {
        const float c = sh[jj][row];      // stride-1 across lanes: conflict-free
        #pragma unroll
        for (int q = 0; q < 8; ++q)
            acc[q] = fmaf(c, Wb[q * 64 + jj], acc[q]);
    }

    const int r = row0 + row;
    if (r < n_rows) {
        if constexpr (OUT_BF16) {
            unsigned int pk[4];
            #pragma unroll
            for (int q = 0; q < 4; ++q) {
                float a0 = fmaxf(acc[2*q],     0.f);
                float a1 = fmaxf(acc[2*q + 1], 0.f);
                pk[q] = (unsigned int)f2bf(a0) | ((unsigned int)f2bf(a1) << 16);
            }
            uint4* dst = (uint4*)((unsigned short*)out + (size_t)r * EMBD + wid * 8);
            *dst = make_uint4(pk[0], pk[1], pk[2], pk[3]);
        } else {
            float* dst = (float*)out + (size_t)r * EMBD + wid * 8;
            ((float4*)dst)[0] = make_float4(fmaxf(acc[0],0.f), fmaxf(acc[1],0.f),
                                            fmaxf(acc[2],0.f), fmaxf(acc[3],0.f));
            ((float4*)dst)[1] = make_float4(fmaxf(acc[4],0.f), fmaxf(acc[5],0.f),
                                            fmaxf(acc[6],0.f), fmaxf(acc[7],0.f));
        }
    }
}

extern "C" void kernel_launch(void* const* d_in, const int* in_sizes, int n_in,
                              void* d_out, int out_size, void* d_ws, size_t ws_size,
                              hipStream_t stream)
{
    // dict order: emb [N,32] f32, W1 [32,64] f32, W2 [32,64] f32,
    //             node_batch [B] i32, neigh [N,10] i32
    const float* emb        = (const float*)d_in[0];
    const float* W1         = (const float*)d_in[1];
    const float* W2         = (const float*)d_in[2];
    const int*   node_batch = (const int*)  d_in[3];
    const int*   neigh      = (const int*)  d_in[4];

    const int N = in_sizes[0] / EMBD;   // 500000
    const int B = in_sizes[3];          // 100000

    unsigned short* emb_bf = (unsigned short*)d_ws;              // 32 MB
    unsigned short* h1_bf  = emb_bf + (size_t)N * EMBD;          // 32 MB

    // 1) emb f32 -> bf16
    const int n4 = (N * EMBD) / 4;
    cvt_bf16_kernel<<<(n4 + 255) / 256, 256, 0, stream>>>(
        (const float4*)emb, (ushort4*)emb_bf, n4);

    // 2) layer 1: all N nodes, h1 stored bf16
    sage_layer<false, true><<<(N + 63) / 64, 256, 0, stream>>>(
        emb_bf, W1, neigh, nullptr, (void*)h1_bf, N);

    // 3) layer 2: batch rows, f32 output
    sage_layer<true, false><<<(B + 63) / 64, 256, 0, stream>>>(
        h1_bf, W2, neigh, node_batch, d_out, B);
}